// Round 5
// baseline (72.638 us; speedup 1.0000x reference)
//
#include <hip/hip_runtime.h>
#include <hip/hip_bf16.h>

#define N_TOK   32768       // 8 * 4096 tokens
#define DPROJ   1024
#define SCALE   32.0f       // sqrt(1024)
#define MAXROWS 32832ull    // worst-case padded rows per bucket (32768 + 64)

typedef short bf16x8 __attribute__((ext_vector_type(8)));
typedef float f32x4  __attribute__((ext_vector_type(4)));

__device__ __forceinline__ short f2bf(float f) {
    unsigned u = __builtin_bit_cast(unsigned, f);
    unsigned r = (u + 0x7FFFu + ((u >> 16) & 1u)) >> 16;   // RNE
    return (short)r;
}

// ---------------------------------------------------------------------------
// Kernel 1: bucketize with per-wave ballot aggregation (4 atomics per wave).
// ---------------------------------------------------------------------------
__global__ void k_bucketize(const int* __restrict__ inp, int* __restrict__ cnt,
                            int* __restrict__ perm, int* __restrict__ rowidx) {
    int i = blockIdx.x * 256 + threadIdx.x;     // N_TOK % 256 == 0
    int t = inp[i];
    int b, l;
    if (t < 20000)       { b = 0; l = 0; }
    else if (t < 40000)  { b = 1; l = 20000; }
    else if (t < 200000) { b = 2; l = 40000; }
    else                 { b = 3; l = 200000; }

    unsigned long long m0 = __ballot(b == 0);
    unsigned long long m1 = __ballot(b == 1);
    unsigned long long m2 = __ballot(b == 2);
    unsigned long long m3 = __ballot(b == 3);

    int lane = threadIdx.x & 63;
    int mybase = 0;
    if (lane < 4) {
        unsigned long long mm = (lane == 0) ? m0 : (lane == 1) ? m1 : (lane == 2) ? m2 : m3;
        mybase = atomicAdd(&cnt[lane], __popcll(mm));
    }
    int base = __shfl(mybase, b);
    unsigned long long mine = (b == 0) ? m0 : (b == 1) ? m1 : (b == 2) ? m2 : m3;
    unsigned long long lt = (lane == 0) ? 0ull : (~0ull >> (64 - lane));
    int pos = base + __popcll(mine & lt);
    perm[b * N_TOK + pos]   = i;
    rowidx[b * N_TOK + pos] = t - l;
}

// ---------------------------------------------------------------------------
// Kernel 2 (after bucketize):
//   blocks [0,768):    transpose+convert proj -> projT[n][k] bf16
//   blocks [768,1284): gather emb rows -> contiguous bucket-sorted bf16 A
// ---------------------------------------------------------------------------
__global__ void k_prep2(const int* __restrict__ cnt,
                        const int* __restrict__ rowidx,
                        const float* __restrict__ p0, const float* __restrict__ p1,
                        const float* __restrict__ p2, const float* __restrict__ p3,
                        short* __restrict__ t0, short* __restrict__ t1,
                        short* __restrict__ t2, short* __restrict__ t3,
                        const float* __restrict__ e0, const float* __restrict__ e1,
                        const float* __restrict__ e2, const float* __restrict__ e3,
                        short* __restrict__ ga0, short* __restrict__ ga1,
                        short* __restrict__ ga2, short* __restrict__ ga3)
{
    __shared__ float tile[128][17];

    if (blockIdx.x < 768) {
        // ---------------- transpose ----------------
        int bid = blockIdx.x;
        const float* src; short* dst; int K; int rel;
        if (bid < 512)      { src = p0; dst = t0; K = 1024; rel = bid; }
        else if (bid < 640) { src = p1; dst = t1; K = 256;  rel = bid - 512; }
        else if (bid < 704) { src = p2; dst = t2; K = 64;   rel = bid - 640; }
        else                { src = p3; dst = t3; K = 16;   rel = bid - 704; }
        int ktiles = (K + 127) >> 7;
        int k0 = (rel % ktiles) * 128;
        int n0 = (rel / ktiles) * 16;
        int t = threadIdx.x;

        #pragma unroll
        for (int i = 0; i < 2; ++i) {
            int idx = t + i * 256;          // 0..511
            int k = idx >> 2;               // 0..127
            int nc = (idx & 3) * 4;         // 0,4,8,12
            if (k0 + k < K) {
                float4 v = *reinterpret_cast<const float4*>(src + (size_t)(k0 + k) * DPROJ + n0 + nc);
                tile[k][nc + 0] = v.x; tile[k][nc + 1] = v.y;
                tile[k][nc + 2] = v.z; tile[k][nc + 3] = v.w;
            }
        }
        __syncthreads();
        int n  = t >> 4;                    // 0..15
        int kc = (t & 15) * 8;              // 0..120
        if (k0 + kc < K) {
            short s[8];
            #pragma unroll
            for (int j = 0; j < 8; ++j) s[j] = f2bf(tile[kc + j][n]);
            *reinterpret_cast<int4*>(dst + (size_t)(n0 + n) * K + k0 + kc) =
                *reinterpret_cast<const int4*>(s);
        }
        return;
    }

    // ---------------- gather A (bucket-sorted, bf16) ----------------
    int bid = blockIdx.x - 768;
    const int c0 = cnt[0], c1 = cnt[1], c2 = cnt[2], c3 = cnt[3];
    const int q0 = (c0 + 63) & ~63;
    const int q1 = q0 + ((c1 + 63) & ~63);
    const int q2 = q1 + ((c2 + 63) & ~63);
    const int q3 = q2 + ((c3 + 63) & ~63);
    const int p0g = bid * 64;
    if (p0g >= q3) return;
    int b, M, m0, K; const float* emb; short* ga;
    if (p0g < q0)      { b = 0; M = c0; m0 = p0g;      K = 1024; emb = e0; ga = ga0; }
    else if (p0g < q1) { b = 1; M = c1; m0 = p0g - q0; K = 256;  emb = e1; ga = ga1; }
    else if (p0g < q2) { b = 2; M = c2; m0 = p0g - q1; K = 64;   emb = e2; ga = ga2; }
    else               { b = 3; M = c3; m0 = p0g - q2; K = 16;   emb = e3; ga = ga3; }
    if (m0 >= M) return;

    const int tid = threadIdx.x;
    const int r   = tid >> 2;           // 0..63
    const int c   = (tid & 3) * 8;      // 0,8,16,24
    const int gm  = m0 + r;
    if (gm >= M) return;
    const int arow = rowidx[b * N_TOK + gm];
    const float* src = emb + (size_t)arow * K;
    short* dst = ga + (size_t)gm * K;

    for (int k0 = 0; k0 < K; k0 += 32) {
        int col = k0 + c;
        if (col < K) {
            float4 x = *reinterpret_cast<const float4*>(src + col);
            float4 y = *reinterpret_cast<const float4*>(src + col + 4);
            short s[8];
            s[0] = f2bf(x.x); s[1] = f2bf(x.y); s[2] = f2bf(x.z); s[3] = f2bf(x.w);
            s[4] = f2bf(y.x); s[5] = f2bf(y.y); s[6] = f2bf(y.z); s[7] = f2bf(y.w);
            *reinterpret_cast<int4*>(dst + col) = *reinterpret_cast<const int4*>(s);
        }
    }
}

// ---------------------------------------------------------------------------
// Kernel 3: fused bf16-MFMA GEMM over all buckets, A pre-gathered bf16.
// BM=64, BN=256, BK=32; 4 waves, each wave: 64 rows x 64 cols (4x4 frags).
// grid(4, 516): x = n-panel -> A-tile re-reads hit L2/L3.
// ---------------------------------------------------------------------------
__global__ __launch_bounds__(256, 3) void k_gemm(
    const short* __restrict__ ga0, const short* __restrict__ ga1,
    const short* __restrict__ ga2, const short* __restrict__ ga3,
    const short* __restrict__ t0, const short* __restrict__ t1,
    const short* __restrict__ t2, const short* __restrict__ t3,
    const int* __restrict__ cnt, const int* __restrict__ perm,
    float* __restrict__ out)
{
    __shared__ short As[64][40];    // stride 80B: b128 frag access is bank-uniform
    __shared__ short Bs[256][40];

    const int c0 = cnt[0], c1 = cnt[1], c2 = cnt[2], c3 = cnt[3];
    const int q0 = (c0 + 63) & ~63;
    const int q1 = q0 + ((c1 + 63) & ~63);
    const int q2 = q1 + ((c2 + 63) & ~63);
    const int q3 = q2 + ((c3 + 63) & ~63);
    const int p0 = blockIdx.y * 64;
    if (p0 >= q3) return;
    int b, M, m0, K; const short* ga; const short* bt;
    if (p0 < q0)      { b = 0; M = c0; m0 = p0;      K = 1024; ga = ga0; bt = t0; }
    else if (p0 < q1) { b = 1; M = c1; m0 = p0 - q0; K = 256;  ga = ga1; bt = t1; }
    else if (p0 < q2) { b = 2; M = c2; m0 = p0 - q1; K = 64;   ga = ga2; bt = t2; }
    else              { b = 3; M = c3; m0 = p0 - q2; K = 16;   ga = ga3; bt = t3; }
    if (m0 >= M) return;
    const int* pperm = perm + b * N_TOK;

    const int tid  = threadIdx.x;
    const int lane = tid & 63;
    const int w    = tid >> 6;
    const int n0   = blockIdx.x * 256;

    // staging indices: thread -> (row, 8-elem chunk)
    const int sr = tid >> 2;            // 0..63
    const int sc = (tid & 3) * 8;       // 0,8,16,24
    const short* aptr = ga + (size_t)(m0 + sr) * K;   // pad rows: benign stale data

    f32x4 acc[4][4];
    #pragma unroll
    for (int mi = 0; mi < 4; ++mi)
        #pragma unroll
        for (int ni = 0; ni < 4; ++ni) acc[mi][ni] = (f32x4)0.0f;

    const int koff = (lane >> 4) * 8;   // same k-bijection for A and B frags
    const int fr   = lane & 15;

    for (int k0 = 0; k0 < K; k0 += 32) {
        // ---- global loads first (overlap with previous tile's MFMA) ----
        int4 a4 = make_int4(0, 0, 0, 0);
        if ((k0 + sc) < K)              // K=16: chunks >=16 stay zero (B also zero there)
            a4 = *reinterpret_cast<const int4*>(aptr + k0 + sc);
        int4 bv[4];
        #pragma unroll
        for (int g = 0; g < 4; ++g) {
            if ((k0 + sc) < K) {
                bv[g] = *reinterpret_cast<const int4*>(
                    bt + (size_t)(n0 + g * 64 + sr) * K + k0 + sc);
            } else {
                bv[g] = make_int4(0, 0, 0, 0);
            }
        }
        __syncthreads();                        // previous tile's frag reads done
        *reinterpret_cast<int4*>(&As[sr][sc]) = a4;
        #pragma unroll
        for (int g = 0; g < 4; ++g)
            *reinterpret_cast<int4*>(&Bs[g * 64 + sr][sc]) = bv[g];
        __syncthreads();

        bf16x8 afr[4], bfr[4];
        #pragma unroll
        for (int mi = 0; mi < 4; ++mi)
            afr[mi] = *reinterpret_cast<const bf16x8*>(&As[mi * 16 + fr][koff]);
        #pragma unroll
        for (int ni = 0; ni < 4; ++ni)
            bfr[ni] = *reinterpret_cast<const bf16x8*>(&Bs[w * 64 + ni * 16 + fr][koff]);
        #pragma unroll
        for (int mi = 0; mi < 4; ++mi)
            #pragma unroll
            for (int ni = 0; ni < 4; ++ni)
                acc[mi][ni] = __builtin_amdgcn_mfma_f32_16x16x32_bf16(
                    afr[mi], bfr[ni], acc[mi][ni], 0, 0, 0);
    }

    // ---- epilogue: C/D layout col=lane&15, row=(lane>>4)*4+reg ----
    const int colb = n0 + w * 64 + fr;
    const int rowg = (lane >> 4) * 4;
    #pragma unroll
    for (int mi = 0; mi < 4; ++mi) {
        #pragma unroll
        for (int j = 0; j < 4; ++j) {
            int m = m0 + mi * 16 + rowg + j;
            if (m < M) {
                size_t r = (size_t)pperm[m] * DPROJ + colb;
                out[r]      = acc[mi][0][j] * SCALE;
                out[r + 16] = acc[mi][1][j] * SCALE;
                out[r + 32] = acc[mi][2][j] * SCALE;
                out[r + 48] = acc[mi][3][j] * SCALE;
            }
        }
    }
}

// ---------------------------------------------------------------------------
// Fallback (ws too small): one block per token, direct fp32 dot products.
// ---------------------------------------------------------------------------
__global__ void k_naive(const int* __restrict__ inp,
                        const float* __restrict__ emb0, const float* __restrict__ emb1,
                        const float* __restrict__ emb2, const float* __restrict__ emb3,
                        const float* __restrict__ proj0, const float* __restrict__ proj1,
                        const float* __restrict__ proj2, const float* __restrict__ proj3,
                        float* __restrict__ out)
{
    __shared__ float e[1024];
    int t = inp[blockIdx.x];
    const float* emb; const float* proj; int K, l;
    if (t < 20000)       { emb = emb0; proj = proj0; K = 1024; l = 0; }
    else if (t < 40000)  { emb = emb1; proj = proj1; K = 256;  l = 20000; }
    else if (t < 200000) { emb = emb2; proj = proj2; K = 64;   l = 40000; }
    else                 { emb = emb3; proj = proj3; K = 16;   l = 200000; }
    int tid = threadIdx.x;
    for (int k = tid; k < K; k += 256) e[k] = emb[(size_t)(t - l) * K + k];
    __syncthreads();
    float acc[4] = {0.f, 0.f, 0.f, 0.f};
    for (int k = 0; k < K; ++k) {
        float ek = e[k];
        #pragma unroll
        for (int c = 0; c < 4; ++c)
            acc[c] = fmaf(ek, proj[(size_t)k * DPROJ + tid + 256 * c], acc[c]);
    }
    #pragma unroll
    for (int c = 0; c < 4; ++c)
        out[(size_t)blockIdx.x * DPROJ + tid + 256 * c] = acc[c] * SCALE;
}

extern "C" void kernel_launch(void* const* d_in, const int* in_sizes, int n_in,
                              void* d_out, int out_size, void* d_ws, size_t ws_size,
                              hipStream_t stream) {
    const int*   inp   = (const int*)d_in[0];
    const float* emb0  = (const float*)d_in[1];
    const float* proj0 = (const float*)d_in[2];
    const float* emb1  = (const float*)d_in[3];
    const float* proj1 = (const float*)d_in[4];
    const float* emb2  = (const float*)d_in[5];
    const float* proj2 = (const float*)d_in[6];
    const float* emb3  = (const float*)d_in[7];
    const float* proj3 = (const float*)d_in[8];
    float* out = (float*)d_out;

    // ws layout (256B-aligned regions)
    const size_t off_cnt  = 0;
    const size_t off_perm = 256;
    const size_t off_row  = off_perm + 4ull * N_TOK * 4;
    const size_t off_t0   = off_row  + 4ull * N_TOK * 4;
    const size_t off_t1   = off_t0 + 1024ull * 1024 * 2;
    const size_t off_t2   = off_t1 + 1024ull * 256 * 2;
    const size_t off_t3   = off_t2 + 1024ull * 64 * 2;
    const size_t off_ga0  = off_t3 + 1024ull * 16 * 2;
    const size_t off_ga1  = off_ga0 + MAXROWS * 1024 * 2;
    const size_t off_ga2  = off_ga1 + MAXROWS * 256 * 2;
    const size_t off_ga3  = off_ga2 + MAXROWS * 64 * 2;
    const size_t needed   = off_ga3 + MAXROWS * 16 * 2;

    if (d_ws == nullptr || ws_size < needed) {
        k_naive<<<N_TOK, 256, 0, stream>>>(inp, emb0, emb1, emb2, emb3,
                                           proj0, proj1, proj2, proj3, out);
        return;
    }

    char* ws = (char*)d_ws;
    int*   cnt    = (int*)(ws + off_cnt);
    int*   perm   = (int*)(ws + off_perm);
    int*   rowidx = (int*)(ws + off_row);
    short* t0     = (short*)(ws + off_t0);
    short* t1     = (short*)(ws + off_t1);
    short* t2     = (short*)(ws + off_t2);
    short* t3     = (short*)(ws + off_t3);
    short* ga0    = (short*)(ws + off_ga0);
    short* ga1    = (short*)(ws + off_ga1);
    short* ga2    = (short*)(ws + off_ga2);
    short* ga3    = (short*)(ws + off_ga3);

    hipMemsetAsync(cnt, 0, 16, stream);
    k_bucketize<<<N_TOK / 256, 256, 0, stream>>>(inp, cnt, perm, rowidx);
    k_prep2<<<768 + 516, 256, 0, stream>>>(cnt, rowidx,
                                           proj0, proj1, proj2, proj3,
                                           t0, t1, t2, t3,
                                           emb0, emb1, emb2, emb3,
                                           ga0, ga1, ga2, ga3);

    dim3 grid(4, 516);      // x = n-panel (adjacent -> A-tile L2/L3 reuse)
    k_gemm<<<grid, 256, 0, stream>>>(ga0, ga1, ga2, ga3,
                                     t0, t1, t2, t3,
                                     cnt, perm, out);
}

// Round 6
// 55.822 us; speedup vs baseline: 1.3012x; 1.3012x over previous
//
#include <hip/hip_runtime.h>
#include <hip/hip_bf16.h>

#define N_TOK   32768       // 8 * 4096 tokens
#define DPROJ   1024
#define SCALE   32.0f       // sqrt(1024)

typedef short bf16x8 __attribute__((ext_vector_type(8)));
typedef float f32x4  __attribute__((ext_vector_type(4)));

__device__ __forceinline__ short f2bf(float f) {
    unsigned u = __builtin_bit_cast(unsigned, f);
    unsigned r = (u + 0x7FFFu + ((u >> 16) & 1u)) >> 16;   // RNE
    return (short)r;
}

// ---------------------------------------------------------------------------
// Fused prep kernel.
//   blocks [0,128):   bucketize (wave-ballot aggregated, 4 atomics per wave)
//   blocks [128,896): transpose+convert proj -> projT[n][k] bf16
// ---------------------------------------------------------------------------
__global__ void k_prep(const int* __restrict__ inp, int* __restrict__ cnt,
                       int* __restrict__ perm, int* __restrict__ rowidx,
                       const float* __restrict__ p0, const float* __restrict__ p1,
                       const float* __restrict__ p2, const float* __restrict__ p3,
                       short* __restrict__ t0, short* __restrict__ t1,
                       short* __restrict__ t2, short* __restrict__ t3)
{
    __shared__ float tile[128][17];

    if (blockIdx.x < 128) {
        // ---------------- bucketize ----------------
        int i = blockIdx.x * 256 + threadIdx.x;
        int t = inp[i];
        int b, l;
        if (t < 20000)       { b = 0; l = 0; }
        else if (t < 40000)  { b = 1; l = 20000; }
        else if (t < 200000) { b = 2; l = 40000; }
        else                 { b = 3; l = 200000; }

        unsigned long long m0 = __ballot(b == 0);
        unsigned long long m1 = __ballot(b == 1);
        unsigned long long m2 = __ballot(b == 2);
        unsigned long long m3 = __ballot(b == 3);

        int lane = threadIdx.x & 63;
        int mybase = 0;
        if (lane < 4) {
            unsigned long long mm = (lane == 0) ? m0 : (lane == 1) ? m1 : (lane == 2) ? m2 : m3;
            mybase = atomicAdd(&cnt[lane], __popcll(mm));
        }
        int base = __shfl(mybase, b);
        unsigned long long mine = (b == 0) ? m0 : (b == 1) ? m1 : (b == 2) ? m2 : m3;
        unsigned long long lt = (lane == 0) ? 0ull : (~0ull >> (64 - lane));
        int pos = base + __popcll(mine & lt);
        perm[b * N_TOK + pos]   = i;
        rowidx[b * N_TOK + pos] = t - l;
        return;
    }

    // ---------------- transpose ----------------
    int bid = blockIdx.x - 128;
    const float* src; short* dst; int K; int rel;
    if (bid < 512)      { src = p0; dst = t0; K = 1024; rel = bid; }
    else if (bid < 640) { src = p1; dst = t1; K = 256;  rel = bid - 512; }
    else if (bid < 704) { src = p2; dst = t2; K = 64;   rel = bid - 640; }
    else                { src = p3; dst = t3; K = 16;   rel = bid - 704; }
    int ktiles = (K + 127) >> 7;
    int k0 = (rel % ktiles) * 128;
    int n0 = (rel / ktiles) * 16;
    int t = threadIdx.x;

    #pragma unroll
    for (int i = 0; i < 2; ++i) {
        int idx = t + i * 256;          // 0..511
        int k = idx >> 2;               // 0..127
        int nc = (idx & 3) * 4;         // 0,4,8,12
        if (k0 + k < K) {
            float4 v = *reinterpret_cast<const float4*>(src + (size_t)(k0 + k) * DPROJ + n0 + nc);
            tile[k][nc + 0] = v.x; tile[k][nc + 1] = v.y;
            tile[k][nc + 2] = v.z; tile[k][nc + 3] = v.w;
        }
    }
    __syncthreads();
    int n  = t >> 4;                    // 0..15
    int kc = (t & 15) * 8;              // 0..120
    if (k0 + kc < K) {
        short s[8];
        #pragma unroll
        for (int j = 0; j < 8; ++j) s[j] = f2bf(tile[kc + j][n]);
        *reinterpret_cast<int4*>(dst + (size_t)(n0 + n) * K + k0 + kc) =
            *reinterpret_cast<const int4*>(s);
    }
}

// ---------------------------------------------------------------------------
// Fused gathered bf16-MFMA GEMM over all buckets.
// BM=64, BN=256, BK=32; 4 waves, each wave: 64 rows x 64 cols (4x4 frags).
// Grid 4x520, dispatch-id remap so all 4 n-panels of one row-tile land on
// the SAME XCD (id%8): hw=y*4+x -> ytile=(hw>>5)*8+(hw&7), panel=(hw>>3)&3.
// K-loop is T14-split: LDS-write(cur) -> issue next tile's global loads ->
// barrier -> MFMA, so load latency hides under MFMA instead of serializing.
// ---------------------------------------------------------------------------
__global__ __launch_bounds__(256, 2) void k_gemm(
    const float* __restrict__ e0, const float* __restrict__ e1,
    const float* __restrict__ e2, const float* __restrict__ e3,
    const short* __restrict__ t0, const short* __restrict__ t1,
    const short* __restrict__ t2, const short* __restrict__ t3,
    const int* __restrict__ cnt, const int* __restrict__ perm,
    const int* __restrict__ rowidx, float* __restrict__ out)
{
    __shared__ short As[64][40];    // stride 80B: b128 frag access is bank-uniform
    __shared__ short Bs[256][40];

    // ---- dispatch-id -> (ytile, panel), XCD-grouped ----
    const int hw     = blockIdx.y * 4 + blockIdx.x;   // HW dispatch order (x fastest)
    const int ytile  = (hw >> 5) * 8 + (hw & 7);
    const int panel  = (hw >> 3) & 3;

    const int c0 = cnt[0], c1 = cnt[1], c2 = cnt[2], c3 = cnt[3];
    const int q0 = (c0 + 63) & ~63;
    const int q1 = q0 + ((c1 + 63) & ~63);
    const int q2 = q1 + ((c2 + 63) & ~63);
    const int q3 = q2 + ((c3 + 63) & ~63);
    const int p0 = ytile * 64;
    if (p0 >= q3) return;
    int b, M, m0, K; const float* emb; const short* bt;
    if (p0 < q0)      { b = 0; M = c0; m0 = p0;      K = 1024; emb = e0; bt = t0; }
    else if (p0 < q1) { b = 1; M = c1; m0 = p0 - q0; K = 256;  emb = e1; bt = t1; }
    else if (p0 < q2) { b = 2; M = c2; m0 = p0 - q1; K = 64;   emb = e2; bt = t2; }
    else              { b = 3; M = c3; m0 = p0 - q2; K = 16;   emb = e3; bt = t3; }
    if (m0 >= M) return;
    const int* pperm = perm   + b * N_TOK;
    const int* prow  = rowidx + b * N_TOK;

    const int tid  = threadIdx.x;
    const int lane = tid & 63;
    const int w    = tid >> 6;
    const int n0   = panel * 256;

    // staging indices: thread -> (row, 8-elem chunk); same for A and B
    const int sr = tid >> 2;            // 0..63
    const int sc = (tid & 3) * 8;       // 0,8,16,24
    const bool avalid = (m0 + sr) < M;
    const int  arow   = avalid ? prow[m0 + sr] : 0;
    const float* aptr = emb + (size_t)arow * K;

    f32x4 acc[4][4];
    #pragma unroll
    for (int mi = 0; mi < 4; ++mi)
        #pragma unroll
        for (int ni = 0; ni < 4; ++ni) acc[mi][ni] = (f32x4)0.0f;

    const int koff = (lane >> 4) * 8;   // same k-bijection for A and B frags
    const int fr   = lane & 15;

    float av[8];
    int4  bv[4];
#define ISSUE_LOADS(K0)                                                        \
    {                                                                          \
        _Pragma("unroll")                                                      \
        for (int j = 0; j < 8; ++j) av[j] = 0.0f;                              \
        if (avalid && ((K0) + sc) < K) {                                       \
            float4 x = *reinterpret_cast<const float4*>(aptr + (K0) + sc);     \
            float4 y = *reinterpret_cast<const float4*>(aptr + (K0) + sc + 4); \
            av[0] = x.x; av[1] = x.y; av[2] = x.z; av[3] = x.w;                \
            av[4] = y.x; av[5] = y.y; av[6] = y.z; av[7] = y.w;                \
        }                                                                      \
        _Pragma("unroll")                                                      \
        for (int g = 0; g < 4; ++g) {                                          \
            if (((K0) + sc) < K)                                               \
                bv[g] = *reinterpret_cast<const int4*>(                        \
                    bt + (size_t)(n0 + g * 64 + sr) * K + (K0) + sc);          \
            else bv[g] = make_int4(0, 0, 0, 0);                                \
        }                                                                      \
    }

    ISSUE_LOADS(0);
    for (int k0 = 0; k0 < K; k0 += 32) {
        __syncthreads();                        // previous tile's frag reads done
        {
            short asv[8];
            #pragma unroll
            for (int j = 0; j < 8; ++j) asv[j] = f2bf(av[j]);
            *reinterpret_cast<int4*>(&As[sr][sc]) = *reinterpret_cast<const int4*>(asv);
            #pragma unroll
            for (int g = 0; g < 4; ++g)
                *reinterpret_cast<int4*>(&Bs[g * 64 + sr][sc]) = bv[g];
        }
        if (k0 + 32 < K) ISSUE_LOADS(k0 + 32);  // issue-early: hide under MFMA
        __syncthreads();

        bf16x8 afr[4], bfr[4];
        #pragma unroll
        for (int mi = 0; mi < 4; ++mi)
            afr[mi] = *reinterpret_cast<const bf16x8*>(&As[mi * 16 + fr][koff]);
        #pragma unroll
        for (int ni = 0; ni < 4; ++ni)
            bfr[ni] = *reinterpret_cast<const bf16x8*>(&Bs[w * 64 + ni * 16 + fr][koff]);
        #pragma unroll
        for (int mi = 0; mi < 4; ++mi)
            #pragma unroll
            for (int ni = 0; ni < 4; ++ni)
                acc[mi][ni] = __builtin_amdgcn_mfma_f32_16x16x32_bf16(
                    afr[mi], bfr[ni], acc[mi][ni], 0, 0, 0);
    }
#undef ISSUE_LOADS

    // ---- epilogue: C/D layout col=lane&15, row=(lane>>4)*4+reg ----
    const int colb = n0 + w * 64 + fr;
    const int rowg = (lane >> 4) * 4;
    #pragma unroll
    for (int mi = 0; mi < 4; ++mi) {
        #pragma unroll
        for (int j = 0; j < 4; ++j) {
            int m = m0 + mi * 16 + rowg + j;
            if (m < M) {
                size_t r = (size_t)pperm[m] * DPROJ + colb;
                out[r]      = acc[mi][0][j] * SCALE;
                out[r + 16] = acc[mi][1][j] * SCALE;
                out[r + 32] = acc[mi][2][j] * SCALE;
                out[r + 48] = acc[mi][3][j] * SCALE;
            }
        }
    }
}

// ---------------------------------------------------------------------------
// Fallback (ws too small): one block per token, direct fp32 dot products.
// ---------------------------------------------------------------------------
__global__ void k_naive(const int* __restrict__ inp,
                        const float* __restrict__ emb0, const float* __restrict__ emb1,
                        const float* __restrict__ emb2, const float* __restrict__ emb3,
                        const float* __restrict__ proj0, const float* __restrict__ proj1,
                        const float* __restrict__ proj2, const float* __restrict__ proj3,
                        float* __restrict__ out)
{
    __shared__ float e[1024];
    int t = inp[blockIdx.x];
    const float* emb; const float* proj; int K, l;
    if (t < 20000)       { emb = emb0; proj = proj0; K = 1024; l = 0; }
    else if (t < 40000)  { emb = emb1; proj = proj1; K = 256;  l = 20000; }
    else if (t < 200000) { emb = emb2; proj = proj2; K = 64;   l = 40000; }
    else                 { emb = emb3; proj = proj3; K = 16;   l = 200000; }
    int tid = threadIdx.x;
    for (int k = tid; k < K; k += 256) e[k] = emb[(size_t)(t - l) * K + k];
    __syncthreads();
    float acc[4] = {0.f, 0.f, 0.f, 0.f};
    for (int k = 0; k < K; ++k) {
        float ek = e[k];
        #pragma unroll
        for (int c = 0; c < 4; ++c)
            acc[c] = fmaf(ek, proj[(size_t)k * DPROJ + tid + 256 * c], acc[c]);
    }
    #pragma unroll
    for (int c = 0; c < 4; ++c)
        out[(size_t)blockIdx.x * DPROJ + tid + 256 * c] = acc[c] * SCALE;
}

extern "C" void kernel_launch(void* const* d_in, const int* in_sizes, int n_in,
                              void* d_out, int out_size, void* d_ws, size_t ws_size,
                              hipStream_t stream) {
    const int*   inp   = (const int*)d_in[0];
    const float* emb0  = (const float*)d_in[1];
    const float* proj0 = (const float*)d_in[2];
    const float* emb1  = (const float*)d_in[3];
    const float* proj1 = (const float*)d_in[4];
    const float* emb2  = (const float*)d_in[5];
    const float* proj2 = (const float*)d_in[6];
    const float* emb3  = (const float*)d_in[7];
    const float* proj3 = (const float*)d_in[8];
    float* out = (float*)d_out;

    // ws layout (256B-aligned regions)
    const size_t off_cnt  = 0;
    const size_t off_perm = 256;
    const size_t off_row  = off_perm + 4ull * N_TOK * 4;
    const size_t off_t0   = off_row  + 4ull * N_TOK * 4;
    const size_t off_t1   = off_t0 + 1024ull * 1024 * 2;
    const size_t off_t2   = off_t1 + 1024ull * 256 * 2;
    const size_t off_t3   = off_t2 + 1024ull * 64 * 2;
    const size_t needed   = off_t3 + 1024ull * 16 * 2;

    if (d_ws == nullptr || ws_size < needed) {
        k_naive<<<N_TOK, 256, 0, stream>>>(inp, emb0, emb1, emb2, emb3,
                                           proj0, proj1, proj2, proj3, out);
        return;
    }

    char* ws = (char*)d_ws;
    int*   cnt    = (int*)(ws + off_cnt);
    int*   perm   = (int*)(ws + off_perm);
    int*   rowidx = (int*)(ws + off_row);
    short* t0     = (short*)(ws + off_t0);
    short* t1     = (short*)(ws + off_t1);
    short* t2     = (short*)(ws + off_t2);
    short* t3     = (short*)(ws + off_t3);

    hipMemsetAsync(cnt, 0, 16, stream);
    k_prep<<<896, 256, 0, stream>>>(inp, cnt, perm, rowidx,
                                    proj0, proj1, proj2, proj3, t0, t1, t2, t3);

    dim3 grid(4, 520);      // 4*520 = 2080 = 65 complete mod-8 chunks (bijective remap)
    k_gemm<<<grid, 256, 0, stream>>>(emb0, emb1, emb2, emb3,
                                     t0, t1, t2, t3,
                                     cnt, perm, rowidx, out);
}

// Round 7
// 54.230 us; speedup vs baseline: 1.3394x; 1.0293x over previous
//
#include <hip/hip_runtime.h>
#include <hip/hip_bf16.h>

#define N_TOK   32768       // 8 * 4096 tokens
#define DPROJ   1024
#define SCALE   32.0f       // sqrt(1024)

typedef short bf16x8 __attribute__((ext_vector_type(8)));
typedef float f32x4  __attribute__((ext_vector_type(4)));

__device__ __forceinline__ short f2bf(float f) {
    unsigned u = __builtin_bit_cast(unsigned, f);
    unsigned r = (u + 0x7FFFu + ((u >> 16) & 1u)) >> 16;   // RNE
    return (short)r;
}

// ---------------------------------------------------------------------------
// Fused prep kernel.
//   blocks [0,128):   bucketize (wave-ballot aggregated, 4 atomics per wave)
//   blocks [128,896): transpose+convert proj -> projT[n][k] bf16
// ---------------------------------------------------------------------------
__global__ void k_prep(const int* __restrict__ inp, int* __restrict__ cnt,
                       int* __restrict__ perm, int* __restrict__ rowidx,
                       const float* __restrict__ p0, const float* __restrict__ p1,
                       const float* __restrict__ p2, const float* __restrict__ p3,
                       short* __restrict__ t0, short* __restrict__ t1,
                       short* __restrict__ t2, short* __restrict__ t3)
{
    __shared__ float tile[128][17];

    if (blockIdx.x < 128) {
        // ---------------- bucketize ----------------
        int i = blockIdx.x * 256 + threadIdx.x;
        int t = inp[i];
        int b, l;
        if (t < 20000)       { b = 0; l = 0; }
        else if (t < 40000)  { b = 1; l = 20000; }
        else if (t < 200000) { b = 2; l = 40000; }
        else                 { b = 3; l = 200000; }

        unsigned long long m0 = __ballot(b == 0);
        unsigned long long m1 = __ballot(b == 1);
        unsigned long long m2 = __ballot(b == 2);
        unsigned long long m3 = __ballot(b == 3);

        int lane = threadIdx.x & 63;
        int mybase = 0;
        if (lane < 4) {
            unsigned long long mm = (lane == 0) ? m0 : (lane == 1) ? m1 : (lane == 2) ? m2 : m3;
            mybase = atomicAdd(&cnt[lane], __popcll(mm));
        }
        int base = __shfl(mybase, b);
        unsigned long long mine = (b == 0) ? m0 : (b == 1) ? m1 : (b == 2) ? m2 : m3;
        unsigned long long lt = (lane == 0) ? 0ull : (~0ull >> (64 - lane));
        int pos = base + __popcll(mine & lt);
        perm[b * N_TOK + pos]   = i;
        rowidx[b * N_TOK + pos] = t - l;
        return;
    }

    // ---------------- transpose ----------------
    int bid = blockIdx.x - 128;
    const float* src; short* dst; int K; int rel;
    if (bid < 512)      { src = p0; dst = t0; K = 1024; rel = bid; }
    else if (bid < 640) { src = p1; dst = t1; K = 256;  rel = bid - 512; }
    else if (bid < 704) { src = p2; dst = t2; K = 64;   rel = bid - 640; }
    else                { src = p3; dst = t3; K = 16;   rel = bid - 704; }
    int ktiles = (K + 127) >> 7;
    int k0 = (rel % ktiles) * 128;
    int n0 = (rel / ktiles) * 16;
    int t = threadIdx.x;

    #pragma unroll
    for (int i = 0; i < 2; ++i) {
        int idx = t + i * 256;          // 0..511
        int k = idx >> 2;               // 0..127
        int nc = (idx & 3) * 4;         // 0,4,8,12
        if (k0 + k < K) {
            float4 v = *reinterpret_cast<const float4*>(src + (size_t)(k0 + k) * DPROJ + n0 + nc);
            tile[k][nc + 0] = v.x; tile[k][nc + 1] = v.y;
            tile[k][nc + 2] = v.z; tile[k][nc + 3] = v.w;
        }
    }
    __syncthreads();
    int n  = t >> 4;                    // 0..15
    int kc = (t & 15) * 8;              // 0..120
    if (k0 + kc < K) {
        short s[8];
        #pragma unroll
        for (int j = 0; j < 8; ++j) s[j] = f2bf(tile[kc + j][n]);
        *reinterpret_cast<int4*>(dst + (size_t)(n0 + n) * K + k0 + kc) =
            *reinterpret_cast<const int4*>(s);
    }
}

// ---------------------------------------------------------------------------
// Fused gathered bf16-MFMA GEMM over all buckets.
// BM=64, BN=256, BK=32; 512 threads / 8 waves, wave-tile 64x32 (4x2 frags,
// acc=32 VGPR) -> whole kernel <=128 VGPR -> 16 waves/CU (4 waves/SIMD),
// doubling latency hiding vs the round-6 4-wave/acc-64 version.
// Grid 4x520, dispatch-id remap so all 4 n-panels of one row-tile land on
// the SAME XCD (id%8). K-loop keeps T14 issue-early staging.
// ---------------------------------------------------------------------------
__global__ __launch_bounds__(512, 4) void k_gemm(
    const float* __restrict__ e0, const float* __restrict__ e1,
    const float* __restrict__ e2, const float* __restrict__ e3,
    const short* __restrict__ t0, const short* __restrict__ t1,
    const short* __restrict__ t2, const short* __restrict__ t3,
    const int* __restrict__ cnt, const int* __restrict__ perm,
    const int* __restrict__ rowidx, float* __restrict__ out)
{
    __shared__ short As[64][40];    // stride 80B: b128 frag access is 2-way (free)
    __shared__ short Bs[256][40];

    // ---- dispatch-id -> (ytile, panel), XCD-grouped ----
    const int hw     = blockIdx.y * 4 + blockIdx.x;   // HW dispatch order (x fastest)
    const int ytile  = (hw >> 5) * 8 + (hw & 7);
    const int panel  = (hw >> 3) & 3;

    const int c0 = cnt[0], c1 = cnt[1], c2 = cnt[2], c3 = cnt[3];
    const int q0 = (c0 + 63) & ~63;
    const int q1 = q0 + ((c1 + 63) & ~63);
    const int q2 = q1 + ((c2 + 63) & ~63);
    const int q3 = q2 + ((c3 + 63) & ~63);
    const int p0 = ytile * 64;
    if (p0 >= q3) return;
    int b, M, m0, K; const float* emb; const short* bt;
    if (p0 < q0)      { b = 0; M = c0; m0 = p0;      K = 1024; emb = e0; bt = t0; }
    else if (p0 < q1) { b = 1; M = c1; m0 = p0 - q0; K = 256;  emb = e1; bt = t1; }
    else if (p0 < q2) { b = 2; M = c2; m0 = p0 - q1; K = 64;   emb = e2; bt = t2; }
    else              { b = 3; M = c3; m0 = p0 - q2; K = 16;   emb = e3; bt = t3; }
    if (m0 >= M) return;
    const int* pperm = perm   + b * N_TOK;
    const int* prow  = rowidx + b * N_TOK;

    const int tid  = threadIdx.x;
    const int lane = tid & 63;
    const int w    = tid >> 6;          // 0..7
    const int n0   = panel * 256;

    // ---- staging indices (512 threads) ----
    // A: 64 rows x 32 k; thread -> (row = tid>>3, 4-elem chunk c4 = (tid&7)*4)
    const int ar = tid >> 3;            // 0..63
    const int ac4 = (tid & 7) * 4;      // 0,4,...,28
    const bool avalid = (m0 + ar) < M;
    const int  arow   = avalid ? prow[m0 + ar] : 0;
    const float* aptr = emb + (size_t)arow * K;
    // B: 256 rows x 32 k; thread -> (row = tid>>1, 16-short half h = (tid&1))
    const int br = tid >> 1;            // 0..255
    const int bh = (tid & 1) * 16;      // 0 or 16 (shorts)

    f32x4 acc[4][2];
    #pragma unroll
    for (int mi = 0; mi < 4; ++mi)
        #pragma unroll
        for (int ni = 0; ni < 2; ++ni) acc[mi][ni] = (f32x4)0.0f;

    const int koff = (lane >> 4) * 8;   // same k-bijection for A and B frags
    const int fr   = lane & 15;

    float4 av;
    int4   bv0, bv1;
#define ISSUE_LOADS(K0)                                                        \
    {                                                                          \
        av = make_float4(0.f, 0.f, 0.f, 0.f);                                  \
        if (avalid && ((K0) + ac4) < K)                                        \
            av = *reinterpret_cast<const float4*>(aptr + (K0) + ac4);          \
        if (((K0) + bh) < K) {                                                 \
            const short* bp = bt + (size_t)(n0 + br) * K + (K0) + bh;          \
            bv0 = *reinterpret_cast<const int4*>(bp);                          \
            bv1 = *reinterpret_cast<const int4*>(bp + 8);                      \
        } else {                                                               \
            bv0 = make_int4(0, 0, 0, 0);                                       \
            bv1 = make_int4(0, 0, 0, 0);                                       \
        }                                                                      \
    }

    ISSUE_LOADS(0);
    for (int k0 = 0; k0 < K; k0 += 32) {
        __syncthreads();                        // previous tile's frag reads done
        {
            short asv[4];
            asv[0] = f2bf(av.x); asv[1] = f2bf(av.y);
            asv[2] = f2bf(av.z); asv[3] = f2bf(av.w);
            *reinterpret_cast<int2*>(&As[ar][ac4]) = *reinterpret_cast<const int2*>(asv);
            *reinterpret_cast<int4*>(&Bs[br][bh])     = bv0;
            *reinterpret_cast<int4*>(&Bs[br][bh + 8]) = bv1;
        }
        if (k0 + 32 < K) ISSUE_LOADS(k0 + 32);  // issue-early: hide under MFMA
        __syncthreads();

        bf16x8 afr[4], bfr[2];
        #pragma unroll
        for (int mi = 0; mi < 4; ++mi)
            afr[mi] = *reinterpret_cast<const bf16x8*>(&As[mi * 16 + fr][koff]);
        #pragma unroll
        for (int ni = 0; ni < 2; ++ni)
            bfr[ni] = *reinterpret_cast<const bf16x8*>(&Bs[w * 32 + ni * 16 + fr][koff]);
        #pragma unroll
        for (int mi = 0; mi < 4; ++mi)
            #pragma unroll
            for (int ni = 0; ni < 2; ++ni)
                acc[mi][ni] = __builtin_amdgcn_mfma_f32_16x16x32_bf16(
                    afr[mi], bfr[ni], acc[mi][ni], 0, 0, 0);
    }
#undef ISSUE_LOADS

    // ---- epilogue: C/D layout col=lane&15, row=(lane>>4)*4+reg ----
    const int colb = n0 + w * 32 + fr;
    const int rowg = (lane >> 4) * 4;
    #pragma unroll
    for (int mi = 0; mi < 4; ++mi) {
        #pragma unroll
        for (int j = 0; j < 4; ++j) {
            int m = m0 + mi * 16 + rowg + j;
            if (m < M) {
                size_t r = (size_t)pperm[m] * DPROJ + colb;
                out[r]      = acc[mi][0][j] * SCALE;
                out[r + 16] = acc[mi][1][j] * SCALE;
            }
        }
    }
}

// ---------------------------------------------------------------------------
// Fallback (ws too small): one block per token, direct fp32 dot products.
// ---------------------------------------------------------------------------
__global__ void k_naive(const int* __restrict__ inp,
                        const float* __restrict__ emb0, const float* __restrict__ emb1,
                        const float* __restrict__ emb2, const float* __restrict__ emb3,
                        const float* __restrict__ proj0, const float* __restrict__ proj1,
                        const float* __restrict__ proj2, const float* __restrict__ proj3,
                        float* __restrict__ out)
{
    __shared__ float e[1024];
    int t = inp[blockIdx.x];
    const float* emb; const float* proj; int K, l;
    if (t < 20000)       { emb = emb0; proj = proj0; K = 1024; l = 0; }
    else if (t < 40000)  { emb = emb1; proj = proj1; K = 256;  l = 20000; }
    else if (t < 200000) { emb = emb2; proj = proj2; K = 64;   l = 40000; }
    else                 { emb = emb3; proj = proj3; K = 16;   l = 200000; }
    int tid = threadIdx.x;
    for (int k = tid; k < K; k += 256) e[k] = emb[(size_t)(t - l) * K + k];
    __syncthreads();
    float acc[4] = {0.f, 0.f, 0.f, 0.f};
    for (int k = 0; k < K; ++k) {
        float ek = e[k];
        #pragma unroll
        for (int c = 0; c < 4; ++c)
            acc[c] = fmaf(ek, proj[(size_t)k * DPROJ + tid + 256 * c], acc[c]);
    }
    #pragma unroll
    for (int c = 0; c < 4; ++c)
        out[(size_t)blockIdx.x * DPROJ + tid + 256 * c] = acc[c] * SCALE;
}

extern "C" void kernel_launch(void* const* d_in, const int* in_sizes, int n_in,
                              void* d_out, int out_size, void* d_ws, size_t ws_size,
                              hipStream_t stream) {
    const int*   inp   = (const int*)d_in[0];
    const float* emb0  = (const float*)d_in[1];
    const float* proj0 = (const float*)d_in[2];
    const float* emb1  = (const float*)d_in[3];
    const float* proj1 = (const float*)d_in[4];
    const float* emb2  = (const float*)d_in[5];
    const float* proj2 = (const float*)d_in[6];
    const float* emb3  = (const float*)d_in[7];
    const float* proj3 = (const float*)d_in[8];
    float* out = (float*)d_out;

    // ws layout (256B-aligned regions)
    const size_t off_cnt  = 0;
    const size_t off_perm = 256;
    const size_t off_row  = off_perm + 4ull * N_TOK * 4;
    const size_t off_t0   = off_row  + 4ull * N_TOK * 4;
    const size_t off_t1   = off_t0 + 1024ull * 1024 * 2;
    const size_t off_t2   = off_t1 + 1024ull * 256 * 2;
    const size_t off_t3   = off_t2 + 1024ull * 64 * 2;
    const size_t needed   = off_t3 + 1024ull * 16 * 2;

    if (d_ws == nullptr || ws_size < needed) {
        k_naive<<<N_TOK, 256, 0, stream>>>(inp, emb0, emb1, emb2, emb3,
                                           proj0, proj1, proj2, proj3, out);
        return;
    }

    char* ws = (char*)d_ws;
    int*   cnt    = (int*)(ws + off_cnt);
    int*   perm   = (int*)(ws + off_perm);
    int*   rowidx = (int*)(ws + off_row);
    short* t0     = (short*)(ws + off_t0);
    short* t1     = (short*)(ws + off_t1);
    short* t2     = (short*)(ws + off_t2);
    short* t3     = (short*)(ws + off_t3);

    hipMemsetAsync(cnt, 0, 16, stream);
    k_prep<<<896, 256, 0, stream>>>(inp, cnt, perm, rowidx,
                                    proj0, proj1, proj2, proj3, t0, t1, t2, t3);

    dim3 grid(4, 520);      // 4*520 = 2080 = 65 complete mod-8 chunks (bijective remap)
    k_gemm<<<grid, 512, 0, stream>>>(emb0, emb1, emb2, emb3,
                                     t0, t1, t2, t3,
                                     cnt, perm, rowidx, out);
}